// Round 9
// baseline (466.339 us; speedup 1.0000x reference)
//
#include <hip/hip_runtime.h>
#include <hip/hip_fp16.h>
#include <stdint.h>

// Problem constants (fixed by the reference)
#define N_ 16384
#define M_ 4096
#define D_ 256
#define O_ 256

// Workspace layout (bytes), total ~10.4 MB
#define WS_T    0          // float[N]      exp(sf+ba)     64 KB
#define WS_U    65536      // float[M]      exp(sc)        16 KB
#define WS_R    81920      // float[D]      colsum(Hc)      1 KB
#define WS_LSUM 98304      // float[N]      row denoms     64 KB
#define WS_WTP  163840     // ushort        Wt packed f16 128 KB
#define WS_BP   294912     // ushort        Hc packed f16   2 MB
#define WS_ABM  2392064    // u64[N*64]     adj bit-matrix  8 MB

typedef float  f32x4  __attribute__((ext_vector_type(4)));
typedef _Float16 half8 __attribute__((ext_vector_type(8)));

// fp32 -> f16 bits (RNE)
__device__ __forceinline__ unsigned short f2h(float f) {
  __half h = __float2half(f);
  unsigned short u;
  __builtin_memcpy(&u, &h, 2);
  return u;
}
// pack two fp32 -> f16x2 bits
__device__ __forceinline__ uint32_t hpack(float a, float b) {
  __half2 h = __floats2half2_rn(a, b);
  uint32_t u;
  __builtin_memcpy(&u, &h, 4);
  return u;
}

// ---------------------------------------------------------------------------
// Merged prep: blocks [0,4096) rowdot(Hf)->tv, [4096,5120) rowdot(Hc)->uv,
// [5120,5376) hc_pack (BP f16 + colsum->Rv), [5376,5408) wt_pack f16.
__global__ __launch_bounds__(256) void prep_kernel(
    const float* __restrict__ Hf, const float* __restrict__ Hc,
    const float* __restrict__ wa, const float* __restrict__ ba,
    const float* __restrict__ Wt, float* __restrict__ tv,
    float* __restrict__ uv, unsigned short* __restrict__ BP,
    unsigned short* __restrict__ WtP, float* __restrict__ Rv) {
  __shared__ float tile[64][65];
  __shared__ float red[4][64];
  int b = blockIdx.x;
  int t = threadIdx.x;
  if (b < 5120) {
    int wv = t >> 6, lane = t & 63;
    const float* X; const float* w; const float* bias; float* outv; int row;
    if (b < 4096) { X = Hf; w = wa;      bias = ba;      outv = tv; row = b * 4 + wv; }
    else          { X = Hc; w = wa + D_; bias = nullptr; outv = uv; row = (b - 4096) * 4 + wv; }
    const float4* x4 = (const float4*)(X + (size_t)row * D_);
    const float4* w4 = (const float4*)w;
    float4 xa = x4[lane], wa4 = w4[lane];
    float s = xa.x * wa4.x + xa.y * wa4.y + xa.z * wa4.z + xa.w * wa4.w;
#pragma unroll
    for (int off = 32; off > 0; off >>= 1) s += __shfl_xor(s, off);
    if (lane == 0) outv[row] = expf(s + (bias ? bias[0] : 0.0f));
  } else if (b < 5376) {
    int bb = b - 5120;
    int bk = bb >> 2;   // 64 tiles along M (k)
    int bc = bb & 3;    // 4 tiles along D (col)
    int k0 = bk * 64, col0 = bc * 64;
    int lane = t & 63, wv = t >> 6;
    int m = lane & 15, q = lane >> 4;
    float colsum = 0.0f;
#pragma unroll
    for (int i = 0; i < 16; ++i) {
      int e = t + 256 * i;
      int kk = e >> 6, cc = e & 63;
      float v = Hc[(size_t)(k0 + kk) * D_ + col0 + cc];
      tile[kk][cc] = v;
      colsum += v;
    }
    red[wv][t & 63] = colsum;
    __syncthreads();
    if (t < 64)
      atomicAdd(&Rv[col0 + t], red[0][t] + red[1][t] + red[2][t] + red[3][t]);
#pragma unroll
    for (int t8 = 0; t8 < 2; ++t8) {
      int tile_id = t8 * 4 + wv;
      int sub = tile_id >> 2, g = tile_id & 3;
      int kgg = bk * 2 + sub;
      int cgg = bc * 4 + g;
      unsigned short v8[8];
#pragma unroll
      for (int j = 0; j < 8; ++j)
        v8[j] = f2h(tile[sub * 32 + q * 8 + j][g * 16 + m]);
      *(uint4*)(BP + ((size_t)(kgg * 16 + cgg) * 64 + lane) * 8) = *(uint4*)v8;
    }
  } else {
    int tt = (b - 5376) * 256 + t;    // 0..8191
    int lane = tt & 63, cg = (tt >> 6) & 15, kg = tt >> 10;
    int m = lane & 15, q = lane >> 4;
    const float* src = Wt + (size_t)(cg * 16 + m) * D_ + kg * 32 + q * 8;
    float4 w0 = *(const float4*)src, w1 = *(const float4*)(src + 4);
    unsigned short v8[8];
    v8[0] = f2h(w0.x); v8[1] = f2h(w0.y); v8[2] = f2h(w0.z); v8[3] = f2h(w0.w);
    v8[4] = f2h(w1.x); v8[5] = f2h(w1.y); v8[6] = f2h(w1.z); v8[7] = f2h(w1.w);
    *(uint4*)(WtP + (size_t)tt * 8) = *(uint4*)v8;
  }
}

// ---------------------------------------------------------------------------
// pack_bits (R2-proven, ~45 us @ ~6 TB/s): dedicated full-occupancy adj
// streamer. Row-contiguous stream, depth-1 prefetch, 8 blocks/CU; __ballot
// packs 64 k-contiguous bits; exact Lsum[r] = t_r*sum(adj*u) - sum(adj).
// R5-R8 lesson: fusing this stream into the MFMA kernel throttles it to
// ~1 TB/s (burst issue at 16 waves/CU); it must own the machine.
__global__ __launch_bounds__(256) void pack_bits_kernel(
    const float* __restrict__ adj, const float* __restrict__ tv,
    const float* __restrict__ uv, unsigned long long* __restrict__ ABM,
    float* __restrict__ Lsum) {
  __shared__ float u_lds[M_];   // 16 KB
  int tid = threadIdx.x;
  int w = tid >> 6, lane = tid & 63;
  for (int i = tid; i < M_; i += 256) u_lds[i] = uv[i];
  __syncthreads();
  int r0 = (blockIdx.x * 4 + w) * 2;
  const float* arA = adj + (size_t)r0 * M_;
  const float* arB = arA + M_;
  float suA = 0.f, scA = 0.f, suB = 0.f, scB = 0.f;

  float a0 = arA[lane], a1 = arA[64 + lane], a2 = arA[128 + lane], a3 = arA[192 + lane];
  float b0 = arB[lane], b1 = arB[64 + lane], b2 = arB[128 + lane], b3 = arB[192 + lane];
#pragma unroll 1
  for (int i = 0; i < 16; ++i) {
    int k0 = i * 256;
    int k1 = (i + 1 < 16) ? k0 + 256 : 0;     // wrap: harmless reload
    float na0 = arA[k1 + lane],       na1 = arA[k1 + 64 + lane];
    float na2 = arA[k1 + 128 + lane], na3 = arA[k1 + 192 + lane];
    float nb0 = arB[k1 + lane],       nb1 = arB[k1 + 64 + lane];
    float nb2 = arB[k1 + 128 + lane], nb3 = arB[k1 + 192 + lane];

    unsigned long long wA0 = __ballot(a0 != 0.0f), wA1 = __ballot(a1 != 0.0f);
    unsigned long long wA2 = __ballot(a2 != 0.0f), wA3 = __ballot(a3 != 0.0f);
    unsigned long long wB0 = __ballot(b0 != 0.0f), wB1 = __ballot(b1 != 0.0f);
    unsigned long long wB2 = __ballot(b2 != 0.0f), wB3 = __ballot(b3 != 0.0f);
    suA = fmaf(a0, u_lds[k0 + lane], suA);
    suA = fmaf(a1, u_lds[k0 + 64 + lane], suA);
    suA = fmaf(a2, u_lds[k0 + 128 + lane], suA);
    suA = fmaf(a3, u_lds[k0 + 192 + lane], suA);
    scA += (a0 + a1) + (a2 + a3);
    suB = fmaf(b0, u_lds[k0 + lane], suB);
    suB = fmaf(b1, u_lds[k0 + 64 + lane], suB);
    suB = fmaf(b2, u_lds[k0 + 128 + lane], suB);
    suB = fmaf(b3, u_lds[k0 + 192 + lane], suB);
    scB += (b0 + b1) + (b2 + b3);
    if (lane < 8) {
      int sel = lane & 3;
      unsigned long long vA = sel == 0 ? wA0 : sel == 1 ? wA1 : sel == 2 ? wA2 : wA3;
      unsigned long long vB = sel == 0 ? wB0 : sel == 1 ? wB1 : sel == 2 ? wB2 : wB3;
      int r = (lane < 4) ? r0 : r0 + 1;
      ABM[(size_t)r * 64 + i * 4 + sel] = (lane < 4) ? vA : vB;
    }
    a0 = na0; a1 = na1; a2 = na2; a3 = na3;
    b0 = nb0; b1 = nb1; b2 = nb2; b3 = nb3;
  }
#pragma unroll
  for (int off = 32; off > 0; off >>= 1) {
    suA += __shfl_xor(suA, off); scA += __shfl_xor(scA, off);
    suB += __shfl_xor(suB, off); scB += __shfl_xor(scB, off);
  }
  if (lane == 0) {
    Lsum[r0] = tv[r0] * suA - scA;
    Lsum[r0 + 1] = tv[r0 + 1] * suB - scB;
  }
}

// ---------------------------------------------------------------------------
// A-fragment from 8 adj bits (R5-proven): slot j = bit_j ? (t*u_j - 1) : 0.
// One v_pk_fma_f16 per pair; mask via BFE/BFI idioms; 0x0000 mask = exact +0.
__device__ __forceinline__ half8 frag_f16(uint32_t bits, __half2 th,
                                          const __half2* up, __half2 mone) {
  union { half8 h; uint32_t u[4]; } r;
#pragma unroll
  for (int p = 0; p < 4; ++p) {
    __half2 v = __hfma2(th, up[p], mone);
    uint32_t c;
    __builtin_memcpy(&c, &v, 4);
    uint32_t mlo = (uint32_t)((int32_t)(bits << (31 - 2 * p)) >> 31);
    uint32_t mhi = (uint32_t)((int32_t)(bits << (30 - 2 * p)) >> 31);
    r.u[p] = c & ((mlo & 0x0000FFFFu) | (mhi & 0xFFFF0000u));   // v_bfi
  }
  return r.h;
}

// one f16 kstep: 2 row-tiles x 2 col-groups from buffer BUF
#define COMPUTE_K(WB0, WB1, KK, BUF)                                          \
  {                                                                           \
    uint4 uu = *(const uint4*)&u_h2[(KK) * 16 + q * 4];                       \
    __half2 up[4];                                                            \
    __builtin_memcpy(up, &uu, 16);                                            \
    half8 af0 = frag_f16(((WB0) >> sh) & 0xffu, th0, up, mone);               \
    half8 af1 = frag_f16(((WB1) >> sh) & 0xffu, th1, up, mone);               \
    acc[0][0] = __builtin_amdgcn_mfma_f32_16x16x32_f16(af0, BUF[0], acc[0][0], 0, 0, 0); \
    acc[0][1] = __builtin_amdgcn_mfma_f32_16x16x32_f16(af0, BUF[1], acc[0][1], 0, 0, 0); \
    acc[1][0] = __builtin_amdgcn_mfma_f32_16x16x32_f16(af1, BUF[0], acc[1][0], 0, 0, 0); \
    acc[1][1] = __builtin_amdgcn_mfma_f32_16x16x32_f16(af1, BUF[1], acc[1][1], 0, 0, 0); \
  }

// ---------------------------------------------------------------------------
// GEMM+epilogue: 32-row x 256-col blocks, 512 thr = 8 waves = 8 colq
// (32 cols each, both row-tiles, FULL K) -> no split-K, no Cred pass,
// ZERO barriers in the K-loop (bits + u preloaded once). A-traffic = 8 MB
// bits; B depth-1 register prefetch from L2-resident BP. acc -> attn
// in-register, then attn @ Wt^T fused (R8 epilogue).
// LDS: bt2[32][132] 16.9K | u_h2 8K = 25.1 KB; ~70 VGPR -> 2 blocks/CU.
__global__ __launch_bounds__(512, 4) void gemm_epi_kernel(
    const unsigned int* __restrict__ ABM32, const unsigned short* __restrict__ BP,
    const float* __restrict__ tv, const float* __restrict__ uv,
    const float* __restrict__ Lsum, const float* __restrict__ Rv,
    const float* __restrict__ Hf, const unsigned short* __restrict__ WtP,
    const float* __restrict__ bt, float* __restrict__ out) {
  __shared__ __align__(16) char smem[25088];
  unsigned int (*bt2)[132] = (unsigned int (*)[132])(smem);           // 16896 B
  uint32_t* u_h2 = (uint32_t*)(smem + 16896);                         //  8192 B
  unsigned short (*attn)[264] = (unsigned short (*)[264])(smem);      // 16896 B (aliases bt2; dead after K-loop)

  int tid = threadIdx.x;
  int w = tid >> 6, lane = tid & 63;
  int q = lane >> 4, m = lane & 15;
  int sh = q * 8;
  int i0 = blockIdx.x * 32;

  for (int i = tid; i < M_ / 2; i += 512) {
    float2 u2 = *(const float2*)(uv + 2 * i);
    u_h2[i] = hpack(u2.x, u2.y);
  }
  for (int p = tid; p < 4096; p += 512) {
    int row = p >> 7, word = p & 127;     // coalesced global; 2-way LDS (free)
    bt2[row][word] = ABM32[(size_t)(i0 + row) * 128 + word];
  }

  // B base + first-kstep prefetch (no LDS dep; overlaps the barrier)
  const unsigned short* bbase = BP + (size_t)(w * 2) * 512 + (size_t)lane * 8;
  half8 bufA[2], bufB[2];
  bufA[0] = *(const half8*)(bbase);
  bufA[1] = *(const half8*)(bbase + 512);

  __half2 th0 = __float2half2_rn(tv[i0 + m]);
  __half2 th1 = __float2half2_rn(tv[i0 + 16 + m]);
  const __half2 mone = __float2half2_rn(-1.0f);

  f32x4 acc[2][2];
#pragma unroll
  for (int s = 0; s < 2; ++s)
#pragma unroll
    for (int n = 0; n < 2; ++n) acc[s][n] = (f32x4){0.f, 0.f, 0.f, 0.f};

  __syncthreads();  // bits + u ready; last barrier until K-loop ends

#pragma unroll 1
  for (int it2 = 0; it2 < 64; ++it2) {
    int kg = it2 * 2;
    // bits for 2 ksteps x 2 row-tiles: one ds_read_b64 each
    uint2 W0 = *(const uint2*)&bt2[m][kg];
    uint2 W1 = *(const uint2*)&bt2[16 + m][kg];

    // ---- kstep kg (bufA); prefetch kg+1 into bufB
    bufB[0] = *(const half8*)(bbase + (size_t)(kg + 1) * 8192);
    bufB[1] = *(const half8*)(bbase + (size_t)(kg + 1) * 8192 + 512);
    COMPUTE_K(W0.x, W1.x, kg, bufA)

    // ---- kstep kg+1 (bufB); prefetch kg+2 into bufA (wrap: harmless reload)
    int kn = (it2 + 1 < 64) ? kg + 2 : 0;
    bufA[0] = *(const half8*)(bbase + (size_t)kn * 8192);
    bufA[1] = *(const half8*)(bbase + (size_t)kn * 8192 + 512);
    COMPUTE_K(W0.y, W1.y, kg + 1, bufB)
  }
  __syncthreads();  // all waves done with bt2 before attn overwrites it

  // ---- attn = (acc + R)/(Lsum + M) + Hf -> f16 LDS (in-register, no Cred)
  {
    float rv0 = Rv[w * 32 + m];
    float rv1 = Rv[w * 32 + 16 + m];
#pragma unroll
    for (int rt = 0; rt < 2; ++rt)
#pragma unroll
      for (int r = 0; r < 4; ++r) {
        int row = rt * 16 + q * 4 + r;      // C/D: row=(lane>>4)*4+reg
        size_t grow = (size_t)i0 + row;
        float invL = 1.0f / (Lsum[grow] + (float)M_);
        float h0 = Hf[grow * D_ + w * 32 + m];
        float h1 = Hf[grow * D_ + w * 32 + 16 + m];
        attn[row][w * 32 + m]      = f2h(fmaf(acc[rt][0][r] + rv0, invL, h0));
        attn[row][w * 32 + 16 + m] = f2h(fmaf(acc[rt][1][r] + rv1, invL, h1));
      }
  }
  __syncthreads();

  // ---- out = relu(attn @ Wt^T + bt). 8 waves = 2 rt2 x 4 cq.
  {
    int rt2 = w & 1, cq = w >> 1;       // rows rt2*16.., cols cq*64..
    f32x4 facc[4];
#pragma unroll
    for (int n = 0; n < 4; ++n) facc[n] = (f32x4){0.f, 0.f, 0.f, 0.f};
    const unsigned short* wwave = WtP + (size_t)(cq * 4) * 512 + (size_t)lane * 8;
#pragma unroll
    for (int kf = 0; kf < 8; ++kf) {
      half8 af = *(const half8*)&attn[rt2 * 16 + m][kf * 32 + q * 8];
#pragma unroll
      for (int n = 0; n < 4; ++n) {
        half8 bf = *(const half8*)(wwave + ((size_t)kf * 16 + n) * 512);
        facc[n] = __builtin_amdgcn_mfma_f32_16x16x32_f16(af, bf, facc[n], 0, 0, 0);
      }
    }
#pragma unroll
    for (int n = 0; n < 4; ++n) {
      int col = cq * 64 + n * 16 + m;
      float b = bt[col];
#pragma unroll
      for (int r = 0; r < 4; ++r) {
        size_t row = (size_t)i0 + rt2 * 16 + q * 4 + r;
        out[row * O_ + col] = fmaxf(facc[n][r] + b, 0.0f);
      }
    }
  }
}

// ---------------------------------------------------------------------------
extern "C" void kernel_launch(void* const* d_in, const int* in_sizes, int n_in,
                              void* d_out, int out_size, void* d_ws, size_t ws_size,
                              hipStream_t stream) {
  const float* Hf  = (const float*)d_in[0];  // [N,D]
  const float* Hc  = (const float*)d_in[1];  // [M,D]
  const float* adj = (const float*)d_in[2];  // [N,M]
  const float* wa  = (const float*)d_in[3];  // [2D]
  const float* ba  = (const float*)d_in[4];  // [1]
  const float* Wt  = (const float*)d_in[5];  // [O,D]
  const float* bt  = (const float*)d_in[6];  // [O]
  float* out = (float*)d_out;

  char* ws = (char*)d_ws;
  float* tv   = (float*)(ws + WS_T);
  float* uv   = (float*)(ws + WS_U);
  float* Rv   = (float*)(ws + WS_R);
  float* Lsum = (float*)(ws + WS_LSUM);
  unsigned short* WtP = (unsigned short*)(ws + WS_WTP);
  unsigned short* BP  = (unsigned short*)(ws + WS_BP);
  unsigned long long* ABM = (unsigned long long*)(ws + WS_ABM);

  hipMemsetAsync(Rv, 0, D_ * sizeof(float), stream);  // atomic target

  prep_kernel<<<5408, 256, 0, stream>>>(Hf, Hc, wa, ba, Wt, tv, uv, BP, WtP, Rv);
  pack_bits_kernel<<<2048, 256, 0, stream>>>(adj, tv, uv, ABM, Lsum);
  gemm_epi_kernel<<<N_ / 32, 512, 0, stream>>>((const unsigned int*)ABM, BP, tv, uv,
                                               Lsum, Rv, Hf, WtP, bt, out);
}

// Round 10
// 453.447 us; speedup vs baseline: 1.0284x; 1.0284x over previous
//
#include <hip/hip_runtime.h>
#include <hip/hip_fp16.h>
#include <stdint.h>

// Problem constants (fixed by the reference)
#define N_ 16384
#define M_ 4096
#define D_ 256
#define O_ 256

// Workspace layout (bytes), total ~2.3 MB
#define WS_T    0          // float[N]      exp(sf+ba)     64 KB
#define WS_U    65536      // float[M]      exp(sc)        16 KB
#define WS_R    81920      // float[D]      colsum(Hc)      1 KB
#define WS_WTP  98304      // ushort        Wt packed f16 128 KB
#define WS_BP   229376     // ushort        Hc packed f16   2 MB

typedef float  f32x4  __attribute__((ext_vector_type(4)));
typedef _Float16 half8 __attribute__((ext_vector_type(8)));

// fp32 -> f16 bits (RNE)
__device__ __forceinline__ unsigned short f2h(float f) {
  __half h = __float2half(f);
  unsigned short u;
  __builtin_memcpy(&u, &h, 2);
  return u;
}
// pack two fp32 -> f16x2 bits
__device__ __forceinline__ uint32_t hpack(float a, float b) {
  __half2 h = __floats2half2_rn(a, b);
  uint32_t u;
  __builtin_memcpy(&u, &h, 4);
  return u;
}

// ---------------------------------------------------------------------------
// Merged prep (unchanged): blocks [0,4096) rowdot(Hf)->tv, [4096,5120)
// rowdot(Hc)->uv, [5120,5376) hc_pack, [5376,5408) wt_pack.
__global__ __launch_bounds__(256) void prep_kernel(
    const float* __restrict__ Hf, const float* __restrict__ Hc,
    const float* __restrict__ wa, const float* __restrict__ ba,
    const float* __restrict__ Wt, float* __restrict__ tv,
    float* __restrict__ uv, unsigned short* __restrict__ BP,
    unsigned short* __restrict__ WtP, float* __restrict__ Rv) {
  __shared__ float tile[64][65];
  __shared__ float red[4][64];
  int b = blockIdx.x;
  int t = threadIdx.x;
  if (b < 5120) {
    int wv = t >> 6, lane = t & 63;
    const float* X; const float* w; const float* bias; float* outv; int row;
    if (b < 4096) { X = Hf; w = wa;      bias = ba;      outv = tv; row = b * 4 + wv; }
    else          { X = Hc; w = wa + D_; bias = nullptr; outv = uv; row = (b - 4096) * 4 + wv; }
    const float4* x4 = (const float4*)(X + (size_t)row * D_);
    const float4* w4 = (const float4*)w;
    float4 xa = x4[lane], wa4 = w4[lane];
    float s = xa.x * wa4.x + xa.y * wa4.y + xa.z * wa4.z + xa.w * wa4.w;
#pragma unroll
    for (int off = 32; off > 0; off >>= 1) s += __shfl_xor(s, off);
    if (lane == 0) outv[row] = expf(s + (bias ? bias[0] : 0.0f));
  } else if (b < 5376) {
    int bb = b - 5120;
    int bk = bb >> 2;   // 64 tiles along M (k)
    int bc = bb & 3;    // 4 tiles along D (col)
    int k0 = bk * 64, col0 = bc * 64;
    int lane = t & 63, wv = t >> 6;
    int m = lane & 15, q = lane >> 4;
    float colsum = 0.0f;
#pragma unroll
    for (int i = 0; i < 16; ++i) {
      int e = t + 256 * i;
      int kk = e >> 6, cc = e & 63;
      float v = Hc[(size_t)(k0 + kk) * D_ + col0 + cc];
      tile[kk][cc] = v;
      colsum += v;
    }
    red[wv][t & 63] = colsum;
    __syncthreads();
    if (t < 64)
      atomicAdd(&Rv[col0 + t], red[0][t] + red[1][t] + red[2][t] + red[3][t]);
#pragma unroll
    for (int t8 = 0; t8 < 2; ++t8) {
      int tile_id = t8 * 4 + wv;
      int sub = tile_id >> 2, g = tile_id & 3;
      int kgg = bk * 2 + sub;
      int cgg = bc * 4 + g;
      unsigned short v8[8];
#pragma unroll
      for (int j = 0; j < 8; ++j)
        v8[j] = f2h(tile[sub * 32 + q * 8 + j][g * 16 + m]);
      *(uint4*)(BP + ((size_t)(kgg * 16 + cgg) * 64 + lane) * 8) = *(uint4*)v8;
    }
  } else {
    int tt = (b - 5376) * 256 + t;    // 0..8191
    int lane = tt & 63, cg = (tt >> 6) & 15, kg = tt >> 10;
    int m = lane & 15, q = lane >> 4;
    const float* src = Wt + (size_t)(cg * 16 + m) * D_ + kg * 32 + q * 8;
    float4 w0 = *(const float4*)src, w1 = *(const float4*)(src + 4);
    unsigned short v8[8];
    v8[0] = f2h(w0.x); v8[1] = f2h(w0.y); v8[2] = f2h(w0.z); v8[3] = f2h(w0.w);
    v8[4] = f2h(w1.x); v8[5] = f2h(w1.y); v8[6] = f2h(w1.z); v8[7] = f2h(w1.w);
    *(uint4*)(WtP + (size_t)tt * 8) = *(uint4*)v8;
  }
}

// ---------------------------------------------------------------------------
// A-fragment from 8 adj bits (R5-proven): slot j = bit_j ? (t*u_j - 1) : 0.
// One v_pk_fma_f16 per pair; mask via BFE/BFI idioms; 0x0000 mask = exact +0.
__device__ __forceinline__ half8 frag_f16(uint32_t bits, __half2 th,
                                          const __half2* up, __half2 mone) {
  union { half8 h; uint32_t u[4]; } r;
#pragma unroll
  for (int p = 0; p < 4; ++p) {
    __half2 v = __hfma2(th, up[p], mone);
    uint32_t c;
    __builtin_memcpy(&c, &v, 4);
    uint32_t mlo = (uint32_t)((int32_t)(bits << (31 - 2 * p)) >> 31);
    uint32_t mhi = (uint32_t)((int32_t)(bits << (30 - 2 * p)) >> 31);
    r.u[p] = c & ((mlo & 0x0000FFFFu) | (mhi & 0xFFFF0000u));   // v_bfi
  }
  return r.h;
}

// issue global loads of one adj chunk (4 rows x 256 cols) into set {n0..n3}
#define LOADS(n0, n1, n2, n3, KB)                                             \
  _Pragma("unroll")                                                           \
  for (int cc = 0; cc < 4; ++cc) {                                            \
    n0[cc] = ar[(size_t)0 * M_ + (KB) + cc * 64 + lane];                      \
    n1[cc] = ar[(size_t)1 * M_ + (KB) + cc * 64 + lane];                      \
    n2[cc] = ar[(size_t)2 * M_ + (KB) + cc * 64 + lane];                      \
    n3[cc] = ar[(size_t)3 * M_ + (KB) + cc * 64 + lane];                      \
  }

// ballot-pack set {n0..n3} into bits_lds[BUF], accumulate su/sc (exact Lsum)
#define TAIL(n0, n1, n2, n3, BUF, KB)                                         \
  {                                                                           \
    unsigned long long bal0[4], bal1[4], bal2[4], bal3[4];                    \
    _Pragma("unroll")                                                         \
    for (int cc = 0; cc < 4; ++cc) {                                          \
      float uvv = u_lds[(KB) + cc * 64 + lane];                               \
      bal0[cc] = __ballot(n0[cc] != 0.0f);                                    \
      bal1[cc] = __ballot(n1[cc] != 0.0f);                                    \
      bal2[cc] = __ballot(n2[cc] != 0.0f);                                    \
      bal3[cc] = __ballot(n3[cc] != 0.0f);                                    \
      su[0] = fmaf(n0[cc], uvv, su[0]);                                       \
      su[1] = fmaf(n1[cc], uvv, su[1]);                                       \
      su[2] = fmaf(n2[cc], uvv, su[2]);                                       \
      su[3] = fmaf(n3[cc], uvv, su[3]);                                       \
    }                                                                         \
    sc[0] += (n0[0] + n0[1]) + (n0[2] + n0[3]);                               \
    sc[1] += (n1[0] + n1[1]) + (n1[2] + n1[3]);                               \
    sc[2] += (n2[0] + n2[1]) + (n2[2] + n2[3]);                               \
    sc[3] += (n3[0] + n3[1]) + (n3[2] + n3[3]);                               \
    if (lane < 32) {                                                          \
      int rowsel = lane >> 3, ccs = (lane >> 1) & 3, hi = lane & 1;           \
      unsigned long long v0 = ccs == 0 ? bal0[0] : ccs == 1 ? bal0[1] : ccs == 2 ? bal0[2] : bal0[3]; \
      unsigned long long v1 = ccs == 0 ? bal1[0] : ccs == 1 ? bal1[1] : ccs == 2 ? bal1[2] : bal1[3]; \
      unsigned long long v2 = ccs == 0 ? bal2[0] : ccs == 1 ? bal2[1] : ccs == 2 ? bal2[2] : bal2[3]; \
      unsigned long long v3 = ccs == 0 ? bal3[0] : ccs == 1 ? bal3[1] : ccs == 2 ? bal3[2] : bal3[3]; \
      unsigned long long v = rowsel == 0 ? v0 : rowsel == 1 ? v1 : rowsel == 2 ? v2 : v3; \
      bits_lds[BUF][w * 4 + rowsel][ccs * 2 + hi] =                           \
          hi ? (unsigned int)(v >> 32) : (unsigned int)v;                     \
    }                                                                         \
  }

// compute one chunk (8 kg; this wave owns kgc = ks*4..ks*4+3, 8 cg of cgh).
// B reads split 4+4 to cap transient VGPRs (depth-2 adj sets cost +16 regs).
#define COMPUTE(C, BUF)                                                       \
  _Pragma("unroll")                                                           \
  for (int kk = 0; kk < 4; ++kk) {                                            \
    int kgc = ks * 4 + kk, kg = (C) * 8 + kgc;                                \
    uint32_t b32 = bits_lds[BUF][rt * 16 + m][kgc];                           \
    uint4 uu = *(const uint4*)&u_h2[kg * 16 + q * 4];                         \
    const unsigned short* bp = BP + ((size_t)(kg * 16 + cgh * 8)) * 512 + (size_t)lane * 8; \
    __half2 up[4];                                                            \
    __builtin_memcpy(up, &uu, 16);                                            \
    half8 af = frag_f16((b32 >> sh) & 0xffu, th, up, mone);                   \
    {                                                                         \
      half8 bf0 = *(const half8*)(bp);                                        \
      half8 bf1 = *(const half8*)(bp + 512);                                  \
      half8 bf2 = *(const half8*)(bp + 1024);                                 \
      half8 bf3 = *(const half8*)(bp + 1536);                                 \
      acc[0] = __builtin_amdgcn_mfma_f32_16x16x32_f16(af, bf0, acc[0], 0, 0, 0); \
      acc[1] = __builtin_amdgcn_mfma_f32_16x16x32_f16(af, bf1, acc[1], 0, 0, 0); \
      acc[2] = __builtin_amdgcn_mfma_f32_16x16x32_f16(af, bf2, acc[2], 0, 0, 0); \
      acc[3] = __builtin_amdgcn_mfma_f32_16x16x32_f16(af, bf3, acc[3], 0, 0, 0); \
    }                                                                         \
    {                                                                         \
      half8 bf4 = *(const half8*)(bp + 2048);                                 \
      half8 bf5 = *(const half8*)(bp + 2560);                                 \
      half8 bf6 = *(const half8*)(bp + 3072);                                 \
      half8 bf7 = *(const half8*)(bp + 3584);                                 \
      acc[4] = __builtin_amdgcn_mfma_f32_16x16x32_f16(af, bf4, acc[4], 0, 0, 0); \
      acc[5] = __builtin_amdgcn_mfma_f32_16x16x32_f16(af, bf5, acc[5], 0, 0, 0); \
      acc[6] = __builtin_amdgcn_mfma_f32_16x16x32_f16(af, bf6, acc[6], 0, 0, 0); \
      acc[7] = __builtin_amdgcn_mfma_f32_16x16x32_f16(af, bf7, acc[7], 0, 0, 0); \
    }                                                                         \
  }

// ---------------------------------------------------------------------------
// Mega kernel v7 = R7 (measured best, 430.9) + DEPTH-2 chunk prefetch.
// R8 counters pinned the fused plateau: 168 MB delivered in 158 us =
// 1.07 TB/s = ~2 KB avg in flight per CU — the chunk loop's burst-issue
// duty cycle (~15%) starves HBM. Fix: two adj register sets (even/odd
// chunks); loads for chunk c+2 issue at the top of phase c and are consumed
// by TAIL ~2 chunk-times later -> 8 KB/wave outstanding CONTINUOUSLY,
// TAIL's wait lands on ~6000-cycle-old loads. Arithmetic and order are
// bit-identical to R7; loop unrolled x2 so set-parity is static.
// LDS: bits 2x32x9 u32 2.3K | u_f32 16K | u_h2 8K | Cred[32][260] 33.3K |
//      Lsum 128B = 58.9K -> 2 blocks/CU.
__global__ __launch_bounds__(512, 4) void mega_kernel(
    const float* __restrict__ adj, const unsigned short* __restrict__ BP,
    const float* __restrict__ tv, const float* __restrict__ uv,
    const float* __restrict__ Rv, const float* __restrict__ Hf,
    const unsigned short* __restrict__ WtP, const float* __restrict__ bt,
    float* __restrict__ out) {
  __shared__ __align__(16) char smem[60288];
  unsigned int (*bits_lds)[32][9] = (unsigned int (*)[32][9])(smem);  //  2304 B
  float* u_lds = (float*)(smem + 2304);                               // 16384 B
  uint32_t* u_h2 = (uint32_t*)(smem + 18688);                         //  8192 B
  float (*Cred)[260] = (float (*)[260])(smem + 26880);                // 33280 B
  float* Lsum_lds = (float*)(smem + 60160);                           //   128 B
  unsigned short (*attn)[264] = (unsigned short (*)[264])(smem);      // 16896 B (aliases bits+u_lds, dead by then)

  int tid = threadIdx.x;
  int w = tid >> 6, lane = tid & 63;
  int q = lane >> 4, m = lane & 15;
  int rt = w & 1, cgh = (w >> 1) & 1, ks = w >> 2;
  int sh = q * 8;
  int i0 = blockIdx.x * 32;

  const float* ar = adj + ((size_t)i0 + w * 4) * M_;
  float su[4] = {0.f, 0.f, 0.f, 0.f}, sc[4] = {0.f, 0.f, 0.f, 0.f};
  float aA0[4], aA1[4], aA2[4], aA3[4];   // even-chunk set
  float aB0[4], aB1[4], aB2[4], aB3[4];   // odd-chunk set

  // chunks 0 and 1 issued before anything else (depth-2 from the start)
  LOADS(aA0, aA1, aA2, aA3, 0)
  LOADS(aB0, aB1, aB2, aB3, 256)

  // u: f32 copy (stream fmas) + packed half2 copy (frag builds)
  for (int i = tid; i < M_ / 2; i += 512) {
    float2 u2 = *(const float2*)(uv + 2 * i);
    u_lds[2 * i] = u2.x; u_lds[2 * i + 1] = u2.y;
    u_h2[i] = hpack(u2.x, u2.y);
  }

  __half2 th = __float2half2_rn(tv[i0 + rt * 16 + m]);
  const __half2 mone = __float2half2_rn(-1.0f);

  f32x4 acc[8];
#pragma unroll
  for (int n = 0; n < 8; ++n) acc[n] = (f32x4){0.f, 0.f, 0.f, 0.f};

  __syncthreads();                 // u ready
  TAIL(aA0, aA1, aA2, aA3, 0, 0)   // chunk 0 -> buf 0 (set A free)
  __syncthreads();                 // bits buf0 ready

#pragma unroll 1
  for (int cc2 = 0; cc2 < 8; ++cc2) {
    int c = cc2 * 2;
    // ---- even phase: compute chunk c (buf0); set A holds even chunks
    if (c + 2 < 16) { LOADS(aA0, aA1, aA2, aA3, (c + 2) * 256) }
    COMPUTE(c, 0)
    TAIL(aB0, aB1, aB2, aB3, 1, (c + 1) * 256)   // chunk c+1 -> buf1
    __syncthreads();
    // ---- odd phase: compute chunk c+1 (buf1); set B holds odd chunks
    int c1 = c + 1;
    if (c1 + 2 < 16) { LOADS(aB0, aB1, aB2, aB3, (c1 + 2) * 256) }
    COMPUTE(c1, 1)
    if (c1 + 1 < 16) { TAIL(aA0, aA1, aA2, aA3, 0, (c1 + 1) * 256) }
    __syncthreads();
  }

  // Lsum (exact): per-row t*sum(adj*u) - sum(adj)
#pragma unroll
  for (int off = 32; off > 0; off >>= 1) {
    su[0] += __shfl_xor(su[0], off); sc[0] += __shfl_xor(sc[0], off);
    su[1] += __shfl_xor(su[1], off); sc[1] += __shfl_xor(sc[1], off);
    su[2] += __shfl_xor(su[2], off); sc[2] += __shfl_xor(sc[2], off);
    su[3] += __shfl_xor(su[3], off); sc[3] += __shfl_xor(sc[3], off);
  }
  if (lane == 0) {
#pragma unroll
    for (int j = 0; j < 4; ++j)
      Lsum_lds[w * 4 + j] = tv[i0 + w * 4 + j] * su[j] - sc[j];
  }

  // ---- Phase 2: sequential ks-plane reduction into fp32 Cred (exact)
#pragma unroll
  for (int s4 = 0; s4 < 2; ++s4) {
    if (ks == s4) {
#pragma unroll
      for (int g = 0; g < 8; ++g) {
        int col = (cgh * 8 + g) * 16 + m;
#pragma unroll
        for (int r = 0; r < 4; ++r) {
          int rl = rt * 16 + q * 4 + r;   // C/D: row=(lane>>4)*4+reg
          if (s4 == 0) Cred[rl][col] = acc[g][r];
          else         Cred[rl][col] += acc[g][r];
        }
      }
    }
    __syncthreads();
  }

  // ---- Phase 3a: attn = (Cred + R)/(Lsum + M) + Hf -> f16 LDS
  {
    int row = tid >> 4;                 // 0..31, 16 threads per row
    int c0 = (tid & 15) * 16;           // 16 consecutive cols per thread
    size_t grow = (size_t)i0 + row;
    float invL = 1.0f / (Lsum_lds[row] + (float)M_);
    const float* hfp = Hf + grow * D_ + c0;
    const float* rvp = Rv + c0;
    const float* crp = &Cred[row][c0];
#pragma unroll
    for (int g = 0; g < 4; ++g) {
      float4 cv = *(const float4*)(crp + g * 4);
      float4 rv = *(const float4*)(rvp + g * 4);
      float4 hv = *(const float4*)(hfp + g * 4);
      float v0 = fmaf(cv.x + rv.x, invL, hv.x);
      float v1 = fmaf(cv.y + rv.y, invL, hv.y);
      float v2 = fmaf(cv.z + rv.z, invL, hv.z);
      float v3 = fmaf(cv.w + rv.w, invL, hv.w);
      *(uint32_t*)&attn[row][c0 + g * 4]     = hpack(v0, v1);
      *(uint32_t*)&attn[row][c0 + g * 4 + 2] = hpack(v2, v3);
    }
  }
  __syncthreads();

  // ---- Phase 3b: out = relu(attn @ Wt^T + bt). 8 waves = 2 rt2 x 4 cq.
  {
    int rt2 = w & 1, cq = w >> 1;       // rows rt2*16.., cols cq*64..
    f32x4 facc[4];
#pragma unroll
    for (int n = 0; n < 4; ++n) facc[n] = (f32x4){0.f, 0.f, 0.f, 0.f};
    const unsigned short* wwave = WtP + (size_t)(cq * 4) * 512 + (size_t)lane * 8;
#pragma unroll
    for (int kf = 0; kf < 8; ++kf) {
      half8 af = *(const half8*)&attn[rt2 * 16 + m][kf * 32 + q * 8];
#pragma unroll
      for (int n = 0; n < 4; ++n) {
        half8 bf = *(const half8*)(wwave + ((size_t)kf * 16 + n) * 512);
        facc[n] = __builtin_amdgcn_mfma_f32_16x16x32_f16(af, bf, facc[n], 0, 0, 0);
      }
    }
#pragma unroll
    for (int n = 0; n < 4; ++n) {
      int col = cq * 64 + n * 16 + m;
      float b = bt[col];
#pragma unroll
      for (int r = 0; r < 4; ++r) {
        size_t row = (size_t)i0 + rt2 * 16 + q * 4 + r;
        out[row * O_ + col] = fmaxf(facc[n][r] + b, 0.0f);
      }
    }
  }
}

// ---------------------------------------------------------------------------
extern "C" void kernel_launch(void* const* d_in, const int* in_sizes, int n_in,
                              void* d_out, int out_size, void* d_ws, size_t ws_size,
                              hipStream_t stream) {
  const float* Hf  = (const float*)d_in[0];  // [N,D]
  const float* Hc  = (const float*)d_in[1];  // [M,D]
  const float* adj = (const float*)d_in[2];  // [N,M]
  const float* wa  = (const float*)d_in[3];  // [2D]
  const float* ba  = (const float*)d_in[4];  // [1]
  const float* Wt  = (const float*)d_in[5];  // [O,D]
  const float* bt  = (const float*)d_in[6];  // [O]
  float* out = (float*)d_out;

  char* ws = (char*)d_ws;
  float* tv   = (float*)(ws + WS_T);
  float* uv   = (float*)(ws + WS_U);
  float* Rv   = (float*)(ws + WS_R);
  unsigned short* WtP = (unsigned short*)(ws + WS_WTP);
  unsigned short* BP  = (unsigned short*)(ws + WS_BP);

  hipMemsetAsync(Rv, 0, D_ * sizeof(float), stream);  // atomic target

  prep_kernel<<<5408, 256, 0, stream>>>(Hf, Hc, wa, ba, Wt, tv, uv, BP, WtP, Rv);
  mega_kernel<<<512, 512, 0, stream>>>(adj, BP, tv, uv, Rv, Hf, WtP, bt, out);
}

// Round 11
// 429.612 us; speedup vs baseline: 1.0855x; 1.0555x over previous
//
#include <hip/hip_runtime.h>
#include <hip/hip_fp16.h>
#include <stdint.h>

// Problem constants (fixed by the reference)
#define N_ 16384
#define M_ 4096
#define D_ 256
#define O_ 256

// Workspace layout (bytes), total ~2.3 MB
#define WS_T    0          // float[N]      exp(sf+ba)     64 KB
#define WS_U    65536      // float[M]      exp(sc)        16 KB
#define WS_R    81920      // float[D]      colsum(Hc)      1 KB
#define WS_WTP  98304      // ushort        Wt packed f16 128 KB
#define WS_BP   229376     // ushort        Hc packed f16   2 MB

typedef float  f32x4  __attribute__((ext_vector_type(4)));
typedef _Float16 half8 __attribute__((ext_vector_type(8)));

// fp32 -> f16 bits (RNE)
__device__ __forceinline__ unsigned short f2h(float f) {
  __half h = __float2half(f);
  unsigned short u;
  __builtin_memcpy(&u, &h, 2);
  return u;
}
// pack two fp32 -> f16x2 bits
__device__ __forceinline__ uint32_t hpack(float a, float b) {
  __half2 h = __floats2half2_rn(a, b);
  uint32_t u;
  __builtin_memcpy(&u, &h, 4);
  return u;
}

// ---------------------------------------------------------------------------
// Merged prep (unchanged): blocks [0,4096) rowdot(Hf)->tv, [4096,5120)
// rowdot(Hc)->uv, [5120,5376) hc_pack, [5376,5408) wt_pack.
__global__ __launch_bounds__(256) void prep_kernel(
    const float* __restrict__ Hf, const float* __restrict__ Hc,
    const float* __restrict__ wa, const float* __restrict__ ba,
    const float* __restrict__ Wt, float* __restrict__ tv,
    float* __restrict__ uv, unsigned short* __restrict__ BP,
    unsigned short* __restrict__ WtP, float* __restrict__ Rv) {
  __shared__ float tile[64][65];
  __shared__ float red[4][64];
  int b = blockIdx.x;
  int t = threadIdx.x;
  if (b < 5120) {
    int wv = t >> 6, lane = t & 63;
    const float* X; const float* w; const float* bias; float* outv; int row;
    if (b < 4096) { X = Hf; w = wa;      bias = ba;      outv = tv; row = b * 4 + wv; }
    else          { X = Hc; w = wa + D_; bias = nullptr; outv = uv; row = (b - 4096) * 4 + wv; }
    const float4* x4 = (const float4*)(X + (size_t)row * D_);
    const float4* w4 = (const float4*)w;
    float4 xa = x4[lane], wa4 = w4[lane];
    float s = xa.x * wa4.x + xa.y * wa4.y + xa.z * wa4.z + xa.w * wa4.w;
#pragma unroll
    for (int off = 32; off > 0; off >>= 1) s += __shfl_xor(s, off);
    if (lane == 0) outv[row] = expf(s + (bias ? bias[0] : 0.0f));
  } else if (b < 5376) {
    int bb = b - 5120;
    int bk = bb >> 2;   // 64 tiles along M (k)
    int bc = bb & 3;    // 4 tiles along D (col)
    int k0 = bk * 64, col0 = bc * 64;
    int lane = t & 63, wv = t >> 6;
    int m = lane & 15, q = lane >> 4;
    float colsum = 0.0f;
#pragma unroll
    for (int i = 0; i < 16; ++i) {
      int e = t + 256 * i;
      int kk = e >> 6, cc = e & 63;
      float v = Hc[(size_t)(k0 + kk) * D_ + col0 + cc];
      tile[kk][cc] = v;
      colsum += v;
    }
    red[wv][t & 63] = colsum;
    __syncthreads();
    if (t < 64)
      atomicAdd(&Rv[col0 + t], red[0][t] + red[1][t] + red[2][t] + red[3][t]);
#pragma unroll
    for (int t8 = 0; t8 < 2; ++t8) {
      int tile_id = t8 * 4 + wv;
      int sub = tile_id >> 2, g = tile_id & 3;
      int kgg = bk * 2 + sub;
      int cgg = bc * 4 + g;
      unsigned short v8[8];
#pragma unroll
      for (int j = 0; j < 8; ++j)
        v8[j] = f2h(tile[sub * 32 + q * 8 + j][g * 16 + m]);
      *(uint4*)(BP + ((size_t)(kgg * 16 + cgg) * 64 + lane) * 8) = *(uint4*)v8;
    }
  } else {
    int tt = (b - 5376) * 256 + t;    // 0..8191
    int lane = tt & 63, cg = (tt >> 6) & 15, kg = tt >> 10;
    int m = lane & 15, q = lane >> 4;
    const float* src = Wt + (size_t)(cg * 16 + m) * D_ + kg * 32 + q * 8;
    float4 w0 = *(const float4*)src, w1 = *(const float4*)(src + 4);
    unsigned short v8[8];
    v8[0] = f2h(w0.x); v8[1] = f2h(w0.y); v8[2] = f2h(w0.z); v8[3] = f2h(w0.w);
    v8[4] = f2h(w1.x); v8[5] = f2h(w1.y); v8[6] = f2h(w1.z); v8[7] = f2h(w1.w);
    *(uint4*)(WtP + (size_t)tt * 8) = *(uint4*)v8;
  }
}

// ---------------------------------------------------------------------------
// A-fragment from 8 adj bits (R5-proven): slot j = bit_j ? (t*u_j - 1) : 0.
// One v_pk_fma_f16 per pair; mask via BFE/BFI idioms; 0x0000 mask = exact +0.
__device__ __forceinline__ half8 frag_f16(uint32_t bits, __half2 th,
                                          const __half2* up, __half2 mone) {
  union { half8 h; uint32_t u[4]; } r;
#pragma unroll
  for (int p = 0; p < 4; ++p) {
    __half2 v = __hfma2(th, up[p], mone);
    uint32_t c;
    __builtin_memcpy(&c, &v, 4);
    uint32_t mlo = (uint32_t)((int32_t)(bits << (31 - 2 * p)) >> 31);
    uint32_t mhi = (uint32_t)((int32_t)(bits << (30 - 2 * p)) >> 31);
    r.u[p] = c & ((mlo & 0x0000FFFFu) | (mhi & 0xFFFF0000u));   // v_bfi
  }
  return r.h;
}

// stage B chunk C (4 kg = 64 KB, fragment-major) into LDS via reg staging.
// 512 thr x 8 x 16 B; global coalesced, ds_write_b128 conflict-free.
#define STAGE(C)                                                              \
  {                                                                           \
    const uint4* gsrc = (const uint4*)BP + (size_t)(C) * 4096 + tid;          \
    uint4 q0 = gsrc[0],        q1 = gsrc[512],      q2 = gsrc[1024];          \
    uint4 q3 = gsrc[1536],     q4 = gsrc[2048],     q5 = gsrc[2560];          \
    uint4 q6 = gsrc[3072],     q7 = gsrc[3584];                               \
    uint4* ld = (uint4*)B_lds + tid;                                          \
    ld[0] = q0;    ld[512] = q1;  ld[1024] = q2; ld[1536] = q3;               \
    ld[2048] = q4; ld[2560] = q5; ld[3072] = q6; ld[3584] = q7;               \
  }

// issue adj loads for one 128-col chunk (4 rows x 2 x 64) into set {n0..n3}
#define LOADS(n0, n1, n2, n3, KB)                                             \
  _Pragma("unroll")                                                           \
  for (int cc = 0; cc < 2; ++cc) {                                            \
    n0[cc] = ar[(size_t)0 * M_ + (KB) + cc * 64 + lane];                      \
    n1[cc] = ar[(size_t)1 * M_ + (KB) + cc * 64 + lane];                      \
    n2[cc] = ar[(size_t)2 * M_ + (KB) + cc * 64 + lane];                      \
    n3[cc] = ar[(size_t)3 * M_ + (KB) + cc * 64 + lane];                      \
  }

// ballot-pack set {n0..n3} into bits_lds; accumulate su/sc (u from global uv)
#define TAIL(n0, n1, n2, n3, KB)                                              \
  {                                                                           \
    unsigned long long bal0[2], bal1[2], bal2[2], bal3[2];                    \
    _Pragma("unroll")                                                         \
    for (int cc = 0; cc < 2; ++cc) {                                          \
      float uvv = uv[(KB) + cc * 64 + lane];                                  \
      bal0[cc] = __ballot(n0[cc] != 0.0f);                                    \
      bal1[cc] = __ballot(n1[cc] != 0.0f);                                    \
      bal2[cc] = __ballot(n2[cc] != 0.0f);                                    \
      bal3[cc] = __ballot(n3[cc] != 0.0f);                                    \
      su[0] = fmaf(n0[cc], uvv, su[0]);                                       \
      su[1] = fmaf(n1[cc], uvv, su[1]);                                       \
      su[2] = fmaf(n2[cc], uvv, su[2]);                                       \
      su[3] = fmaf(n3[cc], uvv, su[3]);                                       \
    }                                                                         \
    sc[0] += n0[0] + n0[1];                                                   \
    sc[1] += n1[0] + n1[1];                                                   \
    sc[2] += n2[0] + n2[1];                                                   \
    sc[3] += n3[0] + n3[1];                                                   \
    if (lane < 16) {                                                          \
      int rowsel = lane >> 2, ccs = (lane >> 1) & 1, hi = lane & 1;           \
      unsigned long long v0 = ccs ? bal0[1] : bal0[0];                        \
      unsigned long long v1 = ccs ? bal1[1] : bal1[0];                        \
      unsigned long long v2 = ccs ? bal2[1] : bal2[0];                        \
      unsigned long long v3 = ccs ? bal3[1] : bal3[0];                        \
      unsigned long long v = rowsel == 0 ? v0 : rowsel == 1 ? v1              \
                           : rowsel == 2 ? v2 : v3;                           \
      bits_lds[w * 4 + rowsel][lane & 3] =                                    \
          hi ? (unsigned int)(v >> 32) : (unsigned int)v;                     \
    }                                                                         \
  }

// compute one 4-kg chunk from LDS-staged B + LDS bits. Wave = colq (2 cg),
// 2 row-tiles, full K: 4 kg x (2 frag builds + 2 ds_read_b128 B + 4 MFMA).
#define COMPUTE(C)                                                            \
  _Pragma("unroll")                                                           \
  for (int kgc = 0; kgc < 4; ++kgc) {                                         \
    int kg = (C) * 4 + kgc;                                                   \
    uint32_t b0 = bits_lds[m][kgc];                                           \
    uint32_t b1 = bits_lds[16 + m][kgc];                                      \
    uint4 uu = *(const uint4*)&u_h2[kg * 16 + q * 4];                         \
    const unsigned short* bp = B_lds + ((size_t)(kgc * 16 + w * 2) * 64 + lane) * 8; \
    half8 bf0 = *(const half8*)(bp);                                          \
    half8 bf1 = *(const half8*)(bp + 512);                                    \
    __half2 up[4];                                                            \
    __builtin_memcpy(up, &uu, 16);                                            \
    half8 af0 = frag_f16((b0 >> sh) & 0xffu, th0, up, mone);                  \
    half8 af1 = frag_f16((b1 >> sh) & 0xffu, th1, up, mone);                  \
    acc[0][0] = __builtin_amdgcn_mfma_f32_16x16x32_f16(af0, bf0, acc[0][0], 0, 0, 0); \
    acc[0][1] = __builtin_amdgcn_mfma_f32_16x16x32_f16(af0, bf1, acc[0][1], 0, 0, 0); \
    acc[1][0] = __builtin_amdgcn_mfma_f32_16x16x32_f16(af1, bf0, acc[1][0], 0, 0, 0); \
    acc[1][1] = __builtin_amdgcn_mfma_f32_16x16x32_f16(af1, bf1, acc[1][1], 0, 0, 0); \
  }

// ---------------------------------------------------------------------------
// Mega kernel v8: LDS-staged B (canonical GEMM staging) + drain-as-delivery.
// R9 proved the K-loop alone (no adj, no barriers, depth-1 B prefetch) costs
// ~143 us -> the plateau is per-wave B L2-latency chains, NOT the adj stream.
// R10 proved prefetch past a barrier is impossible (compiler drains vmcnt(0)
// at every s_barrier). Design: per 4-kg chunk (128 cols), issue ALL global
// traffic (B-stage 64 KB reg-staged + adj c+1 + TAIL) in one window ending
// at barrier-1 — the drain IS the delivery window (16 waves x 2 KB adj in
// flight/CU covers the 22 KB latency-BW product); COMPUTE then runs
// stall-free from LDS (ds_read_b128, conflict-free). 8 waves = 8 colq,
// full K -> no split-K, no Cred; acc -> attn in-register (R9 epilogue).
// Arithmetic bit-identical to R7. LDS: B 64K | u_h2 8K | bits[32][5] .6K |
// Lsum 128B = 74.5 KB -> 2 blocks/CU. ~95 VGPR.
__global__ __launch_bounds__(512, 4) void mega_kernel(
    const float* __restrict__ adj, const unsigned short* __restrict__ BP,
    const float* __restrict__ tv, const float* __restrict__ uv,
    const float* __restrict__ Rv, const float* __restrict__ Hf,
    const unsigned short* __restrict__ WtP, const float* __restrict__ bt,
    float* __restrict__ out) {
  __shared__ __align__(16) char smem[74496];
  unsigned short* B_lds = (unsigned short*)(smem);                    // 65536 B
  uint32_t* u_h2 = (uint32_t*)(smem + 65536);                         //  8192 B
  unsigned int (*bits_lds)[5] = (unsigned int (*)[5])(smem + 73728);  //   640 B
  float* Lsum_lds = (float*)(smem + 74368);                           //   128 B
  unsigned short (*attn)[264] = (unsigned short (*)[264])(smem);      // 16896 B (aliases B_lds, dead by then)

  int tid = threadIdx.x;
  int w = tid >> 6, lane = tid & 63;
  int q = lane >> 4, m = lane & 15;
  int sh = q * 8;
  int i0 = blockIdx.x * 32;

  const float* ar = adj + ((size_t)i0 + w * 4) * M_;
  float su[4] = {0.f, 0.f, 0.f, 0.f}, sc[4] = {0.f, 0.f, 0.f, 0.f};
  float sA0[2], sA1[2], sA2[2], sA3[2];   // even-chunk adj set
  float sB0[2], sB1[2], sB2[2], sB3[2];   // odd-chunk adj set

  // chunk-0 adj issued first; u_h2 fill overlaps
  LOADS(sA0, sA1, sA2, sA3, 0)
  for (int i = tid; i < M_ / 2; i += 512) {
    float2 u2 = *(const float2*)(uv + 2 * i);
    u_h2[i] = hpack(u2.x, u2.y);
  }

  __half2 th0 = __float2half2_rn(tv[i0 + m]);
  __half2 th1 = __float2half2_rn(tv[i0 + 16 + m]);
  const __half2 mone = __float2half2_rn(-1.0f);

  f32x4 acc[2][2];
#pragma unroll
  for (int s = 0; s < 2; ++s)
#pragma unroll
    for (int n = 0; n < 2; ++n) acc[s][n] = (f32x4){0.f, 0.f, 0.f, 0.f};

#pragma unroll 1
  for (int cc2 = 0; cc2 < 16; ++cc2) {
    int c0 = cc2 * 2;
    // ---- even chunk: adj in set A
    STAGE(c0)
    LOADS(sB0, sB1, sB2, sB3, (c0 + 1) * 128)
    TAIL(sA0, sA1, sA2, sA3, c0 * 128)
    __syncthreads();   // delivery window ends: B tile + bits visible
    COMPUTE(c0)
    __syncthreads();   // B_lds + bits free
    // ---- odd chunk: adj in set B
    int c1 = c0 + 1;
    STAGE(c1)
    if (c1 + 1 < 32) { LOADS(sA0, sA1, sA2, sA3, (c1 + 1) * 128) }
    TAIL(sB0, sB1, sB2, sB3, c1 * 128)
    __syncthreads();
    COMPUTE(c1)
    __syncthreads();
  }

  // ---- Lsum (exact): per-row t*sum(adj*u) - sum(adj); rows w*4..w*4+3
#pragma unroll
  for (int off = 32; off > 0; off >>= 1) {
    su[0] += __shfl_xor(su[0], off); sc[0] += __shfl_xor(sc[0], off);
    su[1] += __shfl_xor(su[1], off); sc[1] += __shfl_xor(sc[1], off);
    su[2] += __shfl_xor(su[2], off); sc[2] += __shfl_xor(sc[2], off);
    su[3] += __shfl_xor(su[3], off); sc[3] += __shfl_xor(sc[3], off);
  }
  if (lane == 0) {
#pragma unroll
    for (int j = 0; j < 4; ++j)
      Lsum_lds[w * 4 + j] = tv[i0 + w * 4 + j] * su[j] - sc[j];
  }
  __syncthreads();

  // ---- attn = (acc + R)/(Lsum + M) + Hf -> f16 LDS (in-register, no Cred)
  {
    float rv0 = Rv[w * 32 + m];
    float rv1 = Rv[w * 32 + 16 + m];
#pragma unroll
    for (int rt = 0; rt < 2; ++rt)
#pragma unroll
      for (int r = 0; r < 4; ++r) {
        int row = rt * 16 + q * 4 + r;      // C/D: row=(lane>>4)*4+reg
        size_t grow = (size_t)i0 + row;
        float invL = 1.0f / (Lsum_lds[row] + (float)M_);
        float h0 = Hf[grow * D_ + w * 32 + m];
        float h1 = Hf[grow * D_ + w * 32 + 16 + m];
        attn[row][w * 32 + m]      = f2h(fmaf(acc[rt][0][r] + rv0, invL, h0));
        attn[row][w * 32 + 16 + m] = f2h(fmaf(acc[rt][1][r] + rv1, invL, h1));
      }
  }
  __syncthreads();

  // ---- out = relu(attn @ Wt^T + bt). 8 waves = 2 rt2 x 4 cq.
  {
    int rt2 = w & 1, cq = w >> 1;       // rows rt2*16.., cols cq*64..
    f32x4 facc[4];
#pragma unroll
    for (int n = 0; n < 4; ++n) facc[n] = (f32x4){0.f, 0.f, 0.f, 0.f};
    const unsigned short* wwave = WtP + (size_t)(cq * 4) * 512 + (size_t)lane * 8;
#pragma unroll
    for (int kf = 0; kf < 8; ++kf) {
      half8 af = *(const half8*)&attn[rt2 * 16 + m][kf * 32 + q * 8];
#pragma unroll
      for (int n = 0; n < 4; ++n) {
        half8 bf = *(const half8*)(wwave + ((size_t)kf * 16 + n) * 512);
        facc[n] = __builtin_amdgcn_mfma_f32_16x16x32_f16(af, bf, facc[n], 0, 0, 0);
      }
    }
#pragma unroll
    for (int n = 0; n < 4; ++n) {
      int col = cq * 64 + n * 16 + m;
      float b = bt[col];
#pragma unroll
      for (int r = 0; r < 4; ++r) {
        size_t row = (size_t)i0 + rt2 * 16 + q * 4 + r;
        out[row * O_ + col] = fmaxf(facc[n][r] + b, 0.0f);
      }
    }
  }
}

// ---------------------------------------------------------------------------
extern "C" void kernel_launch(void* const* d_in, const int* in_sizes, int n_in,
                              void* d_out, int out_size, void* d_ws, size_t ws_size,
                              hipStream_t stream) {
  const float* Hf  = (const float*)d_in[0];  // [N,D]
  const float* Hc  = (const float*)d_in[1];  // [M,D]
  const float* adj = (const float*)d_in[2];  // [N,M]
  const float* wa  = (const float*)d_in[3];  // [2D]
  const float* ba  = (const float*)d_in[4];  // [1]
  const float* Wt  = (const float*)d_in[5];  // [O,D]
  const float* bt  = (const float*)d_in[6];  // [O]
  float* out = (float*)d_out;

  char* ws = (char*)d_ws;
  float* tv   = (float*)(ws + WS_T);
  float* uv   = (float*)(ws + WS_U);
  float* Rv   = (float*)(ws + WS_R);
  unsigned short* WtP = (unsigned short*)(ws + WS_WTP);
  unsigned short* BP  = (unsigned short*)(ws + WS_BP);

  hipMemsetAsync(Rv, 0, D_ * sizeof(float), stream);  // atomic target

  prep_kernel<<<5408, 256, 0, stream>>>(Hf, Hc, wa, ba, Wt, tv, uv, BP, WtP, Rv);
  mega_kernel<<<512, 512, 0, stream>>>(adj, BP, tv, uv, Rv, Hf, WtP, bt, out);
}